// Round 4
// baseline (98.361 us; speedup 1.0000x reference)
//
#include <hip/hip_runtime.h>

// Problem constants (from reference)
#define NS   1000        // N_SAMPLES
#define NB   32          // batch
#define NK   27          // cluster channels
#define KP   28          // padded K (for float4)
#define HW   65536       // 256*256
// sim = 10*exp(-cd/1.0 - gd/0.3) + 3*exp(-cd/0.1)

// ws layout (floats):
//   selc [NB][NS][KP]  : 896000
//   selg [NB][NS][4]   : 128000   (offset 896000)
//   cf   [NS][2]       : 2000     (offset 1024000)
//   keys [1024] (uint) : sorted (pix<<10|orig) (offset 1026048)
#define OFF_SELG 896000
#define OFF_CF   1024000
#define OFF_KEY  1026048

// ---- Kernel A: bitonic sort of (pix, idx) keys, one block ----
__global__ __launch_bounds__(1024) void crf_sort(const int* __restrict__ coords,
                                                 unsigned* __restrict__ keys_out) {
    __shared__ unsigned sk[1024];
    const int t = threadIdx.x;
    unsigned key = 0xFFFFFFFFu;
    if (t < NS) {
        int r = coords[t], c = coords[NS + t];
        key = ((unsigned)(r * 256 + c) << 10) | (unsigned)t;   // pix(16b) | orig(10b)
    }
    sk[t] = key;
    __syncthreads();
    for (int k = 2; k <= 1024; k <<= 1) {
        for (int j = k >> 1; j > 0; j >>= 1) {
            int ixj = t ^ j;
            if (ixj > t) {
                unsigned a = sk[t], b = sk[ixj];
                bool asc = ((t & k) == 0);
                if ((a > b) == asc) { sk[t] = b; sk[ixj] = a; }
            }
            __syncthreads();
        }
    }
    if (t < NS) keys_out[t] = sk[t];
}

// ---- Kernel B: gather in sorted-pixel order (DRAM-page-friendly reads),
//      scatter-write to original slots in ws (L2-absorbed) ----
// thread tid -> (ch, n, s): tid = (ch*NB + n)*NS + s ; consecutive lanes =
// consecutive sorted pixels within ONE channel plane.
__global__ void crf_gather(const float* __restrict__ guidance,
                           const float* __restrict__ clusters,
                           const unsigned* __restrict__ keys,
                           float* __restrict__ ws) {
    int tid = blockIdx.x * 256 + threadIdx.x;
    if (tid >= 32 * NB * NS) return;
    int s  = tid % NS;
    int cn = tid / NS;
    int n  = cn & (NB - 1);
    int ch = cn >> 5;

    unsigned key = keys[s];
    int orig = (int)(key & 1023u);
    int pix  = (int)(key >> 10);

    if (ch < NK) {
        float v = __builtin_nontemporal_load(&clusters[((long)n * NK + ch) * HW + pix]);
        ws[((long)n * NS + orig) * KP + ch] = v;
    } else if (ch == NK) {
        ws[((long)n * NS + orig) * KP + NK] = 0.0f;       // selc pad
    } else if (ch < 31) {
        int g = ch - 28;
        float v = __builtin_nontemporal_load(&guidance[((long)n * 3 + g) * HW + pix]);
        ws[OFF_SELG + ((long)n * NS + orig) * 4 + g] = v;
    } else {
        ws[OFF_SELG + ((long)n * NS + orig) * 4 + 3] = 0.0f;  // selg pad
        if (n == 0) {
            ws[OFF_CF + orig * 2]     = (float)(pix >> 8);
            ws[OFF_CF + orig * 2 + 1] = (float)(pix & 255);
        }
    }
}

#define RA     20          // a-rows per block
#define NCHUNK 50          // NS / RA

// ---- Kernel C: main (unchanged from R3) ----
__global__ __launch_bounds__(512, 4) void crf_main(const float* __restrict__ ws,
                                                   float* __restrict__ out) {
    const int bid = blockIdx.x;
    const int n = bid / NCHUNK;
    const int a0 = (bid - n * NCHUNK) * RA;
    const int t = threadIdx.x;

    const float* __restrict__ selc = ws;
    const float* __restrict__ selg = ws + OFF_SELG;
    const float* __restrict__ cf   = ws + OFF_CF;

    const int b0 = t;
    const int b1raw = t + 512;
    const int b1 = b1raw < NS ? b1raw : NS - 1;

    float4 cb[2][7];
    float gb0[2], gb1[2], gb2[2], xbr[2], xbc[2];
    {
        const int bs[2] = {b0, b1};
        #pragma unroll
        for (int i = 0; i < 2; ++i) {
            const float4* pc = (const float4*)(selc + ((long)n * NS + bs[i]) * KP);
            #pragma unroll
            for (int j = 0; j < 7; ++j) cb[i][j] = pc[j];
            const float* pg = selg + ((long)n * NS + bs[i]) * 4;
            gb0[i] = pg[0]; gb1[i] = pg[1]; gb2[i] = pg[2];
            xbr[i] = cf[bs[i] * 2]; xbc[i] = cf[bs[i] * 2 + 1];
        }
    }

    const bool w1 = (b1raw < NS);

    for (int a = 0; a < RA; ++a) {
        const int arow = n * NS + a0 + a;          // wave-uniform
        const float4* pa = (const float4*)(selc + (long)arow * KP);
        const float* pg = selg + (long)arow * 4;
        const float ga0 = pg[0], ga1 = pg[1], ga2 = pg[2];
        const float xar = cf[(a0 + a) * 2], xac = cf[(a0 + a) * 2 + 1];

        float dot0 = 0.0f, dot1 = 0.0f;
        #pragma unroll
        for (int j = 0; j < 7; ++j) {
            float4 va = pa[j];                     // uniform -> SGPRs
            dot0 += va.x * cb[0][j].x;  dot1 += va.x * cb[1][j].x;
            dot0 += va.y * cb[0][j].y;  dot1 += va.y * cb[1][j].y;
            dot0 += va.z * cb[0][j].z;  dot1 += va.z * cb[1][j].z;
            dot0 += va.w * cb[0][j].w;  dot1 += va.w * cb[1][j].w;
        }

        float* po = out + (long)arow * NS;
        {
            float g0 = ga0 - gb0[0], g1 = ga1 - gb1[0], g2 = ga2 - gb2[0];
            float gd = g0 * g0 + g1 * g1 + g2 * g2;
            float dr = xar - xbr[0], dc = xac - xbc[0];
            float cd = dr * dr + dc * dc;
            float s = 10.0f * __expf(-cd - gd * (1.0f / 0.3f))
                    +  3.0f * __expf(-10.0f * cd);
            __builtin_nontemporal_store(-dot0 * s, &po[b0]);
        }
        {
            float g0 = ga0 - gb0[1], g1 = ga1 - gb1[1], g2 = ga2 - gb2[1];
            float gd = g0 * g0 + g1 * g1 + g2 * g2;
            float dr = xar - xbr[1], dc = xac - xbc[1];
            float cd = dr * dr + dc * dc;
            float s = 10.0f * __expf(-cd - gd * (1.0f / 0.3f))
                    +  3.0f * __expf(-10.0f * cd);
            if (w1) __builtin_nontemporal_store(-dot1 * s, &po[b1raw]);
        }
    }
}

extern "C" void kernel_launch(void* const* d_in, const int* in_sizes, int n_in,
                              void* d_out, int out_size, void* d_ws, size_t ws_size,
                              hipStream_t stream) {
    const float* guidance = (const float*)d_in[0];
    const float* clusters = (const float*)d_in[1];
    const int*   coords   = (const int*)d_in[2];
    float* out = (float*)d_out;
    float* ws  = (float*)d_ws;
    unsigned* keys = (unsigned*)(ws + OFF_KEY);

    crf_sort<<<1, 1024, 0, stream>>>(coords, keys);
    {
        int total = 32 * NB * NS;
        int blocks = (total + 255) / 256;
        crf_gather<<<blocks, 256, 0, stream>>>(guidance, clusters, keys, ws);
    }
    {
        int blocks = NB * NCHUNK;   // 1600
        crf_main<<<blocks, 512, 0, stream>>>(ws, out);
    }
}

// Round 5
// 97.548 us; speedup vs baseline: 1.0083x; 1.0083x over previous
//
#include <hip/hip_runtime.h>
#include <hip/hip_bf16.h>

#define NS 1000
#define NB 32
#define NK 27
#define KT 32          // K padded to 32 for 16x16x32 MFMA
#define HW 65536
// sim = 10*exp(-cd/1.0 - gd/0.3) + 3*exp(-cd/0.1)

// ws layout (float offsets):
//   wsT  : bf16 [NB][NS][KT] = 2,048,000 B  -> floats [0, 512000)
//   selg : f32  [NB][NS][4]  -> offset 512000, 128000 floats
//   cf   : f32  [NS][2]      -> offset 640000, 2000 floats
#define OFF_SELG 512000
#define OFF_CF   640000

typedef __attribute__((ext_vector_type(8))) short short8;
typedef __attribute__((ext_vector_type(4))) float f32x4;

// ---- gather: one thread per (n, i, ch), ch in [0,32) ----
__global__ void crf_gather(const float* __restrict__ guidance,
                           const float* __restrict__ clusters,
                           const int* __restrict__ coords,
                           float* __restrict__ ws) {
    int tid = blockIdx.x * 256 + threadIdx.x;
    if (tid >= NB * NS * 32) return;
    int ch = tid & 31;
    int ni = tid >> 5;
    int n = ni / NS;
    int i = ni - n * NS;
    int r = coords[i];
    int c = coords[NS + i];
    int pix = r * 256 + c;

    __hip_bfloat16* wsT = (__hip_bfloat16*)ws;

    if (ch < NK) {
        float v = __builtin_nontemporal_load(&clusters[((long)n * NK + ch) * HW + pix]);
        wsT[(long)ni * KT + ch] = __float2bfloat16(v);
    } else if (ch == NK) {
        #pragma unroll
        for (int k = NK; k < KT; ++k)
            wsT[(long)ni * KT + k] = __float2bfloat16(0.0f);   // K pad
    } else if (ch < 31) {
        int g = ch - 28;
        float v = __builtin_nontemporal_load(&guidance[((long)n * 3 + g) * HW + pix]);
        ws[OFF_SELG + (long)ni * 4 + g] = v;
    } else {
        if (n == 0) {
            ws[OFF_CF + i * 2]     = (float)r;
            ws[OFF_CF + i * 2 + 1] = (float)c;
        }
    }
}

// ---- main: 64a x 64b tile per block, 4 waves (16 b-cols each), MFMA dots ----
// A/B fragment layout assumption (16x16x32 bf16): lane holds 8 contiguous k,
// row/col = lane&15, k0 = (lane>>4)*8. D: col = lane&15, row = (lane>>4)*4+reg.
__global__ __launch_bounds__(256) void crf_main(const float* __restrict__ ws,
                                                float* __restrict__ out) {
    const int n  = blockIdx.z;
    const int a0 = blockIdx.y * 64;
    const int b0 = blockIdx.x * 64;
    const int t = threadIdx.x;
    const int wave = t >> 6, lane = t & 63;

    const __hip_bfloat16* wsT = (const __hip_bfloat16*)ws;
    const float* __restrict__ selg = ws + OFF_SELG;
    const float* __restrict__ cf   = ws + OFF_CF;

    __shared__ float s_ag[64][6];   // ga0,ga1,ga2,xar,xac per a-row
    if (t < 64) {
        int row = a0 + t; if (row > NS - 1) row = NS - 1;
        const float* pg = selg + ((long)n * NS + row) * 4;
        s_ag[t][0] = pg[0]; s_ag[t][1] = pg[1]; s_ag[t][2] = pg[2];
        s_ag[t][3] = cf[row * 2]; s_ag[t][4] = cf[row * 2 + 1];
    }
    __syncthreads();

    const int lr = lane & 15;
    const int lg = lane >> 4;
    const int ka = lg * 8;

    short8 afrag[4];
    #pragma unroll
    for (int ti = 0; ti < 4; ++ti) {
        int arow = a0 + 16 * ti + lr; if (arow > NS - 1) arow = NS - 1;
        afrag[ti] = *(const short8*)(wsT + ((long)n * NS + arow) * KT + ka);
    }
    const int bcol = b0 + wave * 16 + lr;
    const int bc = bcol > NS - 1 ? NS - 1 : bcol;
    const short8 bfrag = *(const short8*)(wsT + ((long)n * NS + bc) * KT + ka);

    f32x4 acc[4];
    #pragma unroll
    for (int ti = 0; ti < 4; ++ti) {
        f32x4 z = {0.0f, 0.0f, 0.0f, 0.0f};
        acc[ti] = __builtin_amdgcn_mfma_f32_16x16x32_bf16(afrag[ti], bfrag, z, 0, 0, 0);
    }

    const float* pgb = selg + ((long)n * NS + bc) * 4;
    const float gb0 = pgb[0], gb1 = pgb[1], gb2 = pgb[2];
    const float xbr = cf[bc * 2], xbcc = cf[bc * 2 + 1];
    const bool bok = (bcol < NS);

    #pragma unroll
    for (int ti = 0; ti < 4; ++ti) {
        #pragma unroll
        for (int r = 0; r < 4; ++r) {
            const int al = 16 * ti + 4 * lg + r;      // a-row within block tile
            float ga0 = s_ag[al][0], ga1 = s_ag[al][1], ga2 = s_ag[al][2];
            float g0 = ga0 - gb0, g1 = ga1 - gb1, g2 = ga2 - gb2;
            float gd = g0 * g0 + g1 * g1 + g2 * g2;
            float dr = s_ag[al][3] - xbr, dc = s_ag[al][4] - xbcc;
            float cd = dr * dr + dc * dc;
            float s = 10.0f * __expf(-cd - gd * (1.0f / 0.3f))
                    +  3.0f * __expf(-10.0f * cd);
            int a = a0 + al;
            if (bok && a < NS)
                __builtin_nontemporal_store(-acc[ti][r] * s,
                                            &out[((long)n * NS + a) * NS + bcol]);
        }
    }
}

extern "C" void kernel_launch(void* const* d_in, const int* in_sizes, int n_in,
                              void* d_out, int out_size, void* d_ws, size_t ws_size,
                              hipStream_t stream) {
    const float* guidance = (const float*)d_in[0];
    const float* clusters = (const float*)d_in[1];
    const int*   coords   = (const int*)d_in[2];
    float* out = (float*)d_out;
    float* ws  = (float*)d_ws;

    {
        int total = NB * NS * 32;          // 1,024,000
        int blocks = (total + 255) / 256;  // 4000
        crf_gather<<<blocks, 256, 0, stream>>>(guidance, clusters, coords, ws);
    }
    {
        dim3 grid(16, 16, NB);             // 64b x 64a tiles, 32 batches
        crf_main<<<grid, 256, 0, stream>>>(ws, out);
    }
}

// Round 6
// 96.365 us; speedup vs baseline: 1.0207x; 1.0123x over previous
//
#include <hip/hip_runtime.h>
#include <hip/hip_bf16.h>

#define NS 1000
#define NB 32
#define NK 27
#define HW 65536
// sim = 10*exp(-cd - gd/0.3) + 3*exp(-10*cd)
// gd = Pg_a + Pg_b - 2*(ga.gb)  with Pg = |bf16(ga)|^2  (diag-exact)

// ws layout (float offsets):
//   Tc : bf16 [NB][NS][32] clusters (k27-31 zero)  -> floats [0, 512000)
//   Tg : bf16 [NB][NS][8]  guidance (k3-7 zero)    -> floats [512000, 640000)
//   E  : f32  [NB][NS][4]  {xr, xc, Pg, 0}         -> floats [640000, 768000)
#define OFF_TG 512000
#define OFF_E  640000

typedef __attribute__((ext_vector_type(8))) short short8;
typedef __attribute__((ext_vector_type(4))) float f32x4;

// ---- gather: one thread per (n, i, ch), ch in [0,32) ----
__global__ void crf_gather(const float* __restrict__ guidance,
                           const float* __restrict__ clusters,
                           const int* __restrict__ coords,
                           float* __restrict__ ws) {
    int tid = blockIdx.x * 256 + threadIdx.x;
    if (tid >= NB * NS * 32) return;
    int ch = tid & 31;
    int ni = tid >> 5;
    int n = ni / NS;
    int i = ni - n * NS;
    int r = coords[i];
    int c = coords[NS + i];
    int pix = r * 256 + c;

    __hip_bfloat16* Tc = (__hip_bfloat16*)ws;
    __hip_bfloat16* Tg = (__hip_bfloat16*)(ws + OFF_TG);
    float* E = ws + OFF_E;

    if (ch < NK) {
        float v = __builtin_nontemporal_load(&clusters[((long)n * NK + ch) * HW + pix]);
        Tc[(long)ni * 32 + ch] = __float2bfloat16(v);
    } else if (ch == NK) {
        #pragma unroll
        for (int k = NK; k < 32; ++k)
            Tc[(long)ni * 32 + k] = __float2bfloat16(0.0f);
    } else if (ch < 31) {
        int q = ch - 28;
        float v = guidance[((long)n * 3 + q) * HW + pix];
        Tg[(long)ni * 8 + q] = __float2bfloat16(v);
    } else {
        // Pg from the SAME bf16-rounded ga values (diag cancellation)
        float p = 0.0f;
        #pragma unroll
        for (int q = 0; q < 3; ++q) {
            float v = guidance[((long)n * 3 + q) * HW + pix];   // L1/L2 hit (same wave)
            float bv = __bfloat162float(__float2bfloat16(v));
            p += bv * bv;
        }
        #pragma unroll
        for (int k = 3; k < 8; ++k)
            Tg[(long)ni * 8 + k] = __float2bfloat16(0.0f);
        float4 e = {(float)r, (float)c, p, 0.0f};
        *(float4*)(E + (long)ni * 4) = e;
    }
}

// ---- main: 64a x 64b tile per block, 4 waves; 2 MFMA chains; LDS-light ----
// 16x16x32 bf16 layout (verified R5): A/B lane holds 8 contig k, row/col =
// lane&15, k0 = (lane>>4)*8. D: col = lane&15, row = (lane>>4)*4 + reg.
__global__ __launch_bounds__(256) void crf_main(const float* __restrict__ ws,
                                                float* __restrict__ out) {
    const int n  = blockIdx.z;
    const int a0 = blockIdx.y * 64;
    const int b0 = blockIdx.x * 64;
    const int t = threadIdx.x;
    const int wave = t >> 6, lane = t & 63;

    const __hip_bfloat16* Tc = (const __hip_bfloat16*)ws;
    const __hip_bfloat16* Tg = (const __hip_bfloat16*)(ws + OFF_TG);
    const float* E = ws + OFF_E;

    __shared__ float4 sE[64];
    if (t < 64) {
        int row = a0 + t; if (row > NS - 1) row = NS - 1;
        sE[t] = *(const float4*)(E + ((long)n * NS + row) * 4);
    }
    __syncthreads();

    const int lr = lane & 15;
    const int lg = lane >> 4;
    const int ka = lg * 8;

    // b-side fragments + epilogue scalars
    const int bcol = b0 + wave * 16 + lr;
    const int bc = bcol > NS - 1 ? NS - 1 : bcol;
    const short8 bfC = *(const short8*)(Tc + ((long)n * NS + bc) * 32 + ka);
    short8 bfG = {0, 0, 0, 0, 0, 0, 0, 0};
    if (lg == 0) bfG = *(const short8*)(Tg + ((long)n * NS + bc) * 8);
    const float4 Eb = *(const float4*)(E + ((long)n * NS + bc) * 4);

    f32x4 accC[4], accG[4];
    #pragma unroll
    for (int ti = 0; ti < 4; ++ti) {
        int ar = a0 + 16 * ti + lr; if (ar > NS - 1) ar = NS - 1;
        short8 afC = *(const short8*)(Tc + ((long)n * NS + ar) * 32 + ka);
        short8 afG = {0, 0, 0, 0, 0, 0, 0, 0};
        if (lg == 0) afG = *(const short8*)(Tg + ((long)n * NS + ar) * 8);
        f32x4 z = {0.0f, 0.0f, 0.0f, 0.0f};
        accC[ti] = __builtin_amdgcn_mfma_f32_16x16x32_bf16(afC, bfC, z, 0, 0, 0);
        accG[ti] = __builtin_amdgcn_mfma_f32_16x16x32_bf16(afG, bfG, z, 0, 0, 0);
    }

    const bool bok = (bcol < NS);
    const float xbr = Eb.x, xbc = Eb.y, Pgb = Eb.z;

    #pragma unroll
    for (int ti = 0; ti < 4; ++ti) {
        #pragma unroll
        for (int r2 = 0; r2 < 4; ++r2) {
            const int al = 16 * ti + 4 * lg + r2;
            float4 Ea = sE[al];
            float dr = Ea.x - xbr, dc = Ea.y - xbc;
            float cd = dr * dr + dc * dc;
            float gd = Ea.z + Pgb - 2.0f * accG[ti][r2];
            float e1 = __expf(-cd - gd * 3.3333333f);
            float e2 = __expf(-10.0f * cd);
            float s = fmaf(e1, -10.0f, e2 * -3.0f);   // -(10e1+3e2)
            int a = a0 + al;
            if (bok && a < NS)
                __builtin_nontemporal_store(accC[ti][r2] * s,
                                            &out[((long)n * NS + a) * NS + bcol]);
        }
    }
}

extern "C" void kernel_launch(void* const* d_in, const int* in_sizes, int n_in,
                              void* d_out, int out_size, void* d_ws, size_t ws_size,
                              hipStream_t stream) {
    const float* guidance = (const float*)d_in[0];
    const float* clusters = (const float*)d_in[1];
    const int*   coords   = (const int*)d_in[2];
    float* out = (float*)d_out;
    float* ws  = (float*)d_ws;

    {
        int total = NB * NS * 32;          // 1,024,000
        int blocks = (total + 255) / 256;  // 4000
        crf_gather<<<blocks, 256, 0, stream>>>(guidance, clusters, coords, ws);
    }
    {
        dim3 grid(16, 16, NB);             // 64b x 64a tiles, 32 batches
        crf_main<<<grid, 256, 0, stream>>>(ws, out);
    }
}